// Round 1
// baseline (374.735 us; speedup 1.0000x reference)
//
#include <hip/hip_runtime.h>
#include <math.h>

#define BB 8
#define SS 2048
#define DD 64
#define FF 16
#define AA 32
#define HH 4
#define HDD 8
#define OO 64
#define DIN 2112          // D + 2*D*F
#define NCOL 128          // 64 gate cols + 64 proj cols
#define NTOK 16384
#define WPK_ELEMS (DIN * NCOL)

// ---------------- precompute kernel ----------------
// ws layout (floats): [0, WPK_ELEMS) Wpk[k][c] (c<64: Wg[c][k], c>=64: Wp[c-64][k])
//                     [WPK_ELEMS, +256) WP[4][64]
//                     [WPK_ELEMS+256, +4) cP[4]
__global__ __launch_bounds__(1024) void aff_pre(
    const float* __restrict__ Wq, const float* __restrict__ bq,
    const float* __restrict__ Wk1,
    const float* __restrict__ Wqi, const float* __restrict__ bqi,
    const float* __restrict__ Wki,
    const float* __restrict__ Wg, const float* __restrict__ Wp,
    float* __restrict__ ws)
{
    float* wpk = ws;
    float* WP  = ws + WPK_ELEMS;
    float* cP  = WP + 256;
    const int tid = threadIdx.x;
    const int gid = blockIdx.x * 1024 + tid;   // < 270336 exactly

    // transpose weights to k-major [2112][128]
    {
        int k = gid >> 7;          // / 128
        int c = gid & 127;
        float v = (c < 64) ? Wg[(size_t)c * DIN + k] : Wp[(size_t)(c - 64) * DIN + k];
        wpk[gid] = v;
    }

    if (blockIdx.x == 0) {
        __shared__ float u[32];
        if (tid < 32) {
            float s = 0.f;
            #pragma unroll
            for (int a = 0; a < 32; ++a) s += Wki[tid * 32 + a] * Wk1[a];
            u[tid] = s;
        }
        __syncthreads();
        if (tid < 256) {
            const int h = tid >> 6;     // 0..3
            const int d = tid & 63;     // 0..63
            float s = 0.f;
            for (int j = 0; j < 8; ++j) {
                int e = h * 8 + j;
                float wc = 0.f;
                #pragma unroll
                for (int a = 0; a < 32; ++a) wc += Wqi[e * 32 + a] * Wq[a * 64 + d];
                s += u[e] * wc;
            }
            WP[h * 64 + d] = s * 0.35355339059327373f;  // 1/sqrt(8)
            if (d == 0) {
                float sc = 0.f;
                for (int j = 0; j < 8; ++j) {
                    int e = h * 8 + j;
                    float bcv = bqi[e];
                    #pragma unroll
                    for (int a = 0; a < 32; ++a) bcv += Wqi[e * 32 + a] * bq[a];
                    sc += u[e] * bcv;
                }
                cP[h] = sc * 0.35355339059327373f;
            }
        }
    }
}

// ---------------- main fused kernel ----------------
// 1 block = 64 tokens, 1024 threads = 16 waves.
// lane = token; wave w owns output cols {w*4..w*4+3} of gate AND proj (scalar weights).
__global__ __launch_bounds__(1024, 1) void aff_main(
    const float* __restrict__ x,
    const float* __restrict__ fm, const float* __restrict__ fs,
    const float* __restrict__ phase,
    const float* __restrict__ wpk,
    const float* __restrict__ WP, const float* __restrict__ cP,
    const float* __restrict__ bg, const float* __restrict__ bp,
    float* __restrict__ out)
{
    __shared__ __align__(16) float fval[DD * FF];     // 4 KB
    __shared__ __align__(16) float phl[DD * FF];      // 4 KB
    __shared__ __align__(16) float xT[DD * 64];       // 16 KB  [d][t]
    __shared__ __align__(16) float Pl[64 * 5];        // padded stride 5
    __shared__ __align__(16) float acif[256 * 64];    // 64 KB  [k][t]

    const int tid  = threadIdx.x;
    const int lane = tid & 63;
    const int w    = __builtin_amdgcn_readfirstlane(tid >> 6);  // wave id 0..15
    const int t0   = blockIdx.x * 64;

    // stage fval = fm*fs and phase (1024 elems each; tid covers exactly)
    fval[tid] = fm[tid] * fs[tid];
    phl[tid]  = phase[tid];

    // load x -> xT (transposed, k-major)
    {
        int lt = tid >> 4;       // token 0..63
        int jq = tid & 15;       // 16B column group
        float4 xv = *(const float4*)(x + (size_t)(t0 + lt) * DD + jq * 4);
        xT[(jq * 4 + 0) * 64 + lt] = xv.x;
        xT[(jq * 4 + 1) * 64 + lt] = xv.y;
        xT[(jq * 4 + 2) * 64 + lt] = xv.z;
        xT[(jq * 4 + 3) * 64 + lt] = xv.w;
    }
    __syncthreads();

    // P[t][h] = WP[h]·x[t] + cP[h]
    if (tid < 256) {
        int t = tid & 63, h = tid >> 6;
        float acc = cP[h];
        const float* wp = WP + h * 64;
        #pragma unroll 8
        for (int d = 0; d < 64; ++d) acc = fmaf(wp[d], xT[d * 64 + t], acc);
        Pl[t * 5 + h] = acc;
    }
    __syncthreads();

    float ag[4] = {0.f, 0.f, 0.f, 0.f};
    float ap[4] = {0.f, 0.f, 0.f, 0.f};
    const float* wgp = wpk + w * 4;   // base for this wave's cols

    // ---- x part of the projection (k = 0..63) ----
    #pragma unroll 4
    for (int k = 0; k < 64; ++k) {
        float a = xT[k * 64 + lane];
        const float* r = wgp + k * NCOL;
        ag[0] = fmaf(a, r[0],  ag[0]); ag[1] = fmaf(a, r[1],  ag[1]);
        ag[2] = fmaf(a, r[2],  ag[2]); ag[3] = fmaf(a, r[3],  ag[3]);
        ap[0] = fmaf(a, r[64], ap[0]); ap[1] = fmaf(a, r[65], ap[1]);
        ap[2] = fmaf(a, r[66], ap[2]); ap[3] = fmaf(a, r[67], ap[3]);
    }

    // ---- fourier-feature part, 8 chunks of 8 d's (256 k each) ----
    for (int ch = 0; ch < 8; ++ch) {
        __syncthreads();   // previous chunk's matmul reads of acif done
        if (tid < 512) {
            const int t  = lane;
            const int dl = w;                 // 0..7 (wave-uniform)
            const int d  = ch * 8 + dl;
            const float* fv  = fval + d * 16;
            const float* phr = phl  + d * 16;
            float aw[16];
            #pragma unroll
            for (int f = 0; f < 16; ++f) aw[f] = 0.f;
            #pragma unroll
            for (int h = 0; h < 4; ++h) {
                float Ph = Pl[t * 5 + h];
                float sc[16]; float m = -1e30f;
                #pragma unroll
                for (int f = 0; f < 16; ++f) { sc[f] = fv[f] * Ph; m = fmaxf(m, sc[f]); }
                float e[16]; float z = 0.f;
                #pragma unroll
                for (int f = 0; f < 16; ++f) { e[f] = __expf(sc[f] - m); z += e[f]; }
                float inv = 0.25f / z;        // mean over heads folded in
                #pragma unroll
                for (int f = 0; f < 16; ++f) aw[f] = fmaf(e[f], inv, aw[f]);
            }
            float sflt = (float)((t0 + t) & (SS - 1));
            float w2   = 6.283185307179586f * (sflt * (1.0f / 2047.0f));
            #pragma unroll
            for (int f = 0; f < 16; ++f) {
                float ang = fmaf(w2, fv[f], phr[f]);
                acif[(dl * 32 + f)      * 64 + t] = aw[f] * __sinf(ang);
                acif[(dl * 32 + 16 + f) * 64 + t] = aw[f] * __cosf(ang);
            }
        }
        __syncthreads();

        const float* rb = wgp + (64 + ch * 256) * NCOL;
        #pragma unroll 4
        for (int k = 0; k < 256; ++k) {
            float a = acif[k * 64 + lane];
            const float* r = rb + k * NCOL;
            ag[0] = fmaf(a, r[0],  ag[0]); ag[1] = fmaf(a, r[1],  ag[1]);
            ag[2] = fmaf(a, r[2],  ag[2]); ag[3] = fmaf(a, r[3],  ag[3]);
            ap[0] = fmaf(a, r[64], ap[0]); ap[1] = fmaf(a, r[65], ap[1]);
            ap[2] = fmaf(a, r[66], ap[2]); ap[3] = fmaf(a, r[67], ap[3]);
        }
    }

    // ---- epilogue: sigmoid(g)*silu(p) + x, transpose via LDS for coalesced stores ----
    __syncthreads();
    float* outl = acif;   // reuse, stride 68 (padded, 16B-aligned rows)
    #pragma unroll
    for (int oo = 0; oo < 4; ++oo) {
        int o = w * 4 + oo;
        float g = ag[oo] + bg[o];
        float p = ap[oo] + bp[o];
        float sg = 1.0f / (1.0f + __expf(-g));
        float sp = 1.0f / (1.0f + __expf(-p));
        outl[lane * 68 + o] = fmaf(sg * sp, p, xT[o * 64 + lane]);
    }
    __syncthreads();
    {
        int t  = tid >> 4;
        int o0 = (tid & 15) * 4;
        float4 v = *(float4*)(outl + t * 68 + o0);
        *(float4*)(out + (size_t)t0 * DD + tid * 4) = v;
    }
}

extern "C" void kernel_launch(void* const* d_in, const int* in_sizes, int n_in,
                              void* d_out, int out_size, void* d_ws, size_t ws_size,
                              hipStream_t stream) {
    (void)in_sizes; (void)n_in; (void)out_size; (void)ws_size;
    const float* x    = (const float*)d_in[0];
    const float* fm   = (const float*)d_in[1];
    const float* phs  = (const float*)d_in[2];
    const float* fs   = (const float*)d_in[3];
    const float* Wq   = (const float*)d_in[4];
    const float* bq   = (const float*)d_in[5];
    const float* Wk1  = (const float*)d_in[6];
    // d_in[7] = bk1: cancels in softmax, unused
    const float* Wqi  = (const float*)d_in[8];
    const float* bqi  = (const float*)d_in[9];
    const float* Wki  = (const float*)d_in[10];
    // d_in[11] = bki: cancels in softmax, unused
    const float* Wg   = (const float*)d_in[12];
    const float* bg   = (const float*)d_in[13];
    const float* Wp   = (const float*)d_in[14];
    const float* bp   = (const float*)d_in[15];
    float* out = (float*)d_out;
    float* ws  = (float*)d_ws;

    aff_pre<<<WPK_ELEMS / 1024, 1024, 0, stream>>>(Wq, bq, Wk1, Wqi, bqi, Wki, Wg, Wp, ws);

    const float* wpk = ws;
    const float* WP  = ws + WPK_ELEMS;
    const float* cP  = WP + 256;
    aff_main<<<NTOK / 64, 1024, 0, stream>>>(x, fm, fs, phs, wpk, WP, cP, bg, bp, out);
}

// Round 2
// 174.302 us; speedup vs baseline: 2.1499x; 2.1499x over previous
//
#include <hip/hip_runtime.h>
#include <math.h>

#define SS 2048
#define DIN 2112
#define NKT 66            // K tiles of 32
#define TOK 32            // tokens per block
#define NBLK 512
#define ASTR 264          // abuf row stride (bf16): 528 B, 132 dwords == 4 mod 32 -> conflict-free frags
#define XSTR 68           // xs row stride (fp32)
#define XBSTR 72          // xb row stride (bf16): 144 B, 36 dwords == 4 mod 32
#define CSTR 132          // C buffer row stride (fp32)
#define BFRAG_ELEMS (NKT * 8 * 64 * 8)   // 270336 ushort

typedef __attribute__((ext_vector_type(4))) float f32x4;
typedef __attribute__((ext_vector_type(8))) short bf16x8;

__device__ __forceinline__ unsigned short f2bf(float x) {
    union { float f; unsigned u; } v; v.f = x;
    unsigned r = v.u + 0x7FFFu + ((v.u >> 16) & 1u);
    return (unsigned short)(r >> 16);
}

// ---------------- precompute: pack B fragment-major bf16, fold attention to WP/cP ----------------
// ws layout: [0, 540672 B) Bfrag ushort[66][8][64][8]
//            floats at +135168: WP[4][64], then cP[4]
__global__ __launch_bounds__(256) void aff_pre(
    const float* __restrict__ Wq, const float* __restrict__ bq,
    const float* __restrict__ Wk1,
    const float* __restrict__ Wqi, const float* __restrict__ bqi,
    const float* __restrict__ Wki,
    const float* __restrict__ Wg, const float* __restrict__ Wp,
    float* __restrict__ ws)
{
    unsigned short* Bf = (unsigned short*)ws;
    float* WP = ws + 135168;
    float* cP = WP + 256;
    const int tid = threadIdx.x;
    const int gid = blockIdx.x * 256 + tid;   // < 270336 exactly

    {
        // gid bits: j(3) q(2) nl(4) nt(3) kt(rest) -> wave reads 2 rows x 64 B contiguous
        int j  = gid & 7;
        int q  = (gid >> 3) & 3;
        int nl = (gid >> 5) & 15;
        int nt = (gid >> 9) & 7;
        int kt = gid >> 12;
        int k = kt * 32 + q * 8 + j;
        int n = nt * 16 + nl;
        float s = (n < 64) ? Wg[(size_t)n * DIN + k] : Wp[(size_t)(n - 64) * DIN + k];
        int dst = ((kt * 8 + nt) * 64 + q * 16 + nl) * 8 + j;
        Bf[dst] = f2bf(s);
    }

    if (blockIdx.x == 0) {
        __shared__ float u[32];
        if (tid < 32) {
            float s = 0.f;
            #pragma unroll
            for (int a = 0; a < 32; ++a) s += Wki[tid * 32 + a] * Wk1[a];
            u[tid] = s;
        }
        __syncthreads();
        {
            const int h = tid >> 6;     // 0..3
            const int d = tid & 63;     // 0..63
            float s = 0.f;
            for (int j = 0; j < 8; ++j) {
                int e = h * 8 + j;
                float wc = 0.f;
                #pragma unroll
                for (int a = 0; a < 32; ++a) wc += Wqi[e * 32 + a] * Wq[a * 64 + d];
                s += u[e] * wc;
            }
            WP[h * 64 + d] = s * 0.35355339059327373f;  // 1/sqrt(8)
            if (d == 0) {
                float sc = 0.f;
                for (int j = 0; j < 8; ++j) {
                    int e = h * 8 + j;
                    float bcv = bqi[e];
                    #pragma unroll
                    for (int a = 0; a < 32; ++a) bcv += Wqi[e * 32 + a] * bq[a];
                    sc += u[e] * bcv;
                }
                cP[h] = sc * 0.35355339059327373f;
            }
        }
    }
}

// ---------------- main fused kernel: generate A in LDS (bf16), MFMA against packed B ----------------
__global__ __launch_bounds__(256, 4) void aff_main(
    const float* __restrict__ x,
    const float* __restrict__ fm, const float* __restrict__ fs,
    const float* __restrict__ phase,
    const unsigned short* __restrict__ Bf,
    const float* __restrict__ WP, const float* __restrict__ cP,
    const float* __restrict__ bg, const float* __restrict__ bp,
    float* __restrict__ out)
{
    __shared__ __align__(16) float xs[TOK * XSTR];             // 8704 B (fp32 x, epilogue residual)
    __shared__ __align__(16) unsigned short xb[TOK * XBSTR];   // 4608 B (bf16 x, A k=0..63)
    __shared__ __align__(16) unsigned short abuf[TOK * ASTR];  // 16896 B (A chunk / C buffer)
    __shared__ __align__(16) float fv[1024];                   // 4096 B
    __shared__ __align__(16) float ph[1024];                   // 4096 B
    __shared__ float Pl[TOK * 5];                              // 640 B

    const int tid  = threadIdx.x;
    const int lane = tid & 63;
    const int w    = tid >> 6;          // wave 0..3
    const int t0   = blockIdx.x * TOK;
    const int lm   = lane & 15;
    const int lq   = lane >> 4;
    const int mt   = w & 1;             // m-tile of C (16 tokens)
    const int nt0  = (w >> 1) * 4;      // first of 4 n-tiles

    // stage fv = fm*fs and phase (vectorized, 256 float4 each)
    {
        float4 a = ((const float4*)fm)[tid];
        float4 b = ((const float4*)fs)[tid];
        float4 r; r.x = a.x * b.x; r.y = a.y * b.y; r.z = a.z * b.z; r.w = a.w * b.w;
        ((float4*)fv)[tid] = r;
        ((float4*)ph)[tid] = ((const float4*)phase)[tid];
    }
    // stage x (fp32 + bf16)
    #pragma unroll
    for (int i = 0; i < 2; ++i) {
        int idx = tid + i * 256;        // 0..511
        int t = idx >> 4, j4 = (idx & 15) * 4;
        float4 xv = *(const float4*)(x + (size_t)(t0 + t) * 64 + j4);
        *(float4*)(xs + t * XSTR + j4) = xv;
        unsigned short* xbp = xb + t * XBSTR + j4;
        xbp[0] = f2bf(xv.x); xbp[1] = f2bf(xv.y); xbp[2] = f2bf(xv.z); xbp[3] = f2bf(xv.w);
    }
    __syncthreads();

    // P[t][h] = WP[h]·x[t] + cP[h]
    if (tid < 128) {
        int t = tid & 31, h = tid >> 5;
        float acc = cP[h];
        const float* wp = WP + h * 64;
        #pragma unroll 8
        for (int d = 0; d < 64; ++d) acc = fmaf(wp[d], xs[t * XSTR + d], acc);
        Pl[t * 5 + h] = acc;
    }

    f32x4 acc[4] = {};

    // ---- x part (k-tiles 0,1) from xb ----
    #pragma unroll
    for (int ks = 0; ks < 2; ++ks) {
        bf16x8 a = *(const bf16x8*)(xb + (mt * 16 + lm) * XBSTR + ks * 32 + lq * 8);
        const bf16x8* bbase = (const bf16x8*)Bf + (size_t)ks * 8 * 64 + lane;
        #pragma unroll
        for (int i = 0; i < 4; ++i) {
            bf16x8 b = bbase[(nt0 + i) * 64];
            acc[i] = __builtin_amdgcn_mfma_f32_16x16x32_bf16(a, b, acc[i], 0, 0, 0);
        }
    }
    __syncthreads();   // Pl ready

    const int tl = tid & 31;            // token for build phase
    const int dl = tid >> 5;            // d-local 0..7

    for (int ch = 0; ch < 8; ++ch) {
        // ---- build A chunk: 8 d's x 32 (sin|cos) per token ----
        {
            const int d = ch * 8 + dl;
            const float* fvp = fv + d * 16;
            const float* php = ph + d * 16;
            float fl[16], aw[16];
            #pragma unroll
            for (int f = 0; f < 16; ++f) { fl[f] = fvp[f]; aw[f] = 0.f; }
            #pragma unroll
            for (int h = 0; h < 4; ++h) {
                float Ph = Pl[tl * 5 + h];
                float sc[16];
                #pragma unroll
                for (int f = 0; f < 16; ++f) sc[f] = fl[f] * Ph;
                float m = sc[0];
                #pragma unroll
                for (int f = 1; f < 16; ++f) m = fmaxf(m, sc[f]);
                float z = 0.f;
                #pragma unroll
                for (int f = 0; f < 16; ++f) { sc[f] = __expf(sc[f] - m); z += sc[f]; }
                float inv = 0.25f / z;
                #pragma unroll
                for (int f = 0; f < 16; ++f) aw[f] = fmaf(sc[f], inv, aw[f]);
            }
            float w2 = 6.283185307179586f * ((float)((t0 + tl) & (SS - 1)) * (1.0f / 2047.0f));
            unsigned short* dst = abuf + tl * ASTR + dl * 32;
            #pragma unroll
            for (int i2 = 0; i2 < 2; ++i2) {
                uint4 vs, vc;
                unsigned us[4], uc[4];
                #pragma unroll
                for (int jj = 0; jj < 4; ++jj) {
                    int f0 = i2 * 8 + jj * 2;
                    float a0, c0, a1, c1;
                    float ang0 = fmaf(w2, fl[f0], php[f0]);
                    float ang1 = fmaf(w2, fl[f0 + 1], php[f0 + 1]);
                    __sincosf(ang0, &a0, &c0);
                    __sincosf(ang1, &a1, &c1);
                    us[jj] = (unsigned)f2bf(aw[f0] * a0) | ((unsigned)f2bf(aw[f0 + 1] * a1) << 16);
                    uc[jj] = (unsigned)f2bf(aw[f0] * c0) | ((unsigned)f2bf(aw[f0 + 1] * c1) << 16);
                }
                vs.x = us[0]; vs.y = us[1]; vs.z = us[2]; vs.w = us[3];
                vc.x = uc[0]; vc.y = uc[1]; vc.z = uc[2]; vc.w = uc[3];
                *(uint4*)(dst + i2 * 8) = vs;          // sin block: cols dl*32 + [0,16)
                *(uint4*)(dst + 16 + i2 * 8) = vc;     // cos block: cols dl*32 + [16,32)
            }
        }
        __syncthreads();

        // ---- MFMA over this chunk: 8 k-steps of 32 ----
        #pragma unroll
        for (int ks = 0; ks < 8; ++ks) {
            bf16x8 a = *(const bf16x8*)(abuf + (mt * 16 + lm) * ASTR + ks * 32 + lq * 8);
            const bf16x8* bbase = (const bf16x8*)Bf + (size_t)(2 + ch * 8 + ks) * 8 * 64 + lane;
            #pragma unroll
            for (int i = 0; i < 4; ++i) {
                bf16x8 b = bbase[(nt0 + i) * 64];
                acc[i] = __builtin_amdgcn_mfma_f32_16x16x32_bf16(a, b, acc[i], 0, 0, 0);
            }
        }
        __syncthreads();
    }

    // ---- epilogue: frags -> LDS, combine gate/proj, residual, coalesced store ----
    float* Cb = (float*)abuf;
    #pragma unroll
    for (int i = 0; i < 4; ++i) {
        #pragma unroll
        for (int r = 0; r < 4; ++r) {
            Cb[(mt * 16 + lq * 4 + r) * CSTR + (nt0 + i) * 16 + lm] = acc[i][r];
        }
    }
    __syncthreads();
    #pragma unroll
    for (int it = 0; it < 2; ++it) {
        int t = (tid >> 4) + it * 16;
        int o0 = (tid & 15) * 4;
        float4 g4 = *(float4*)(Cb + t * CSTR + o0);
        float4 p4 = *(float4*)(Cb + t * CSTR + 64 + o0);
        float4 bg4 = *(const float4*)(bg + o0);
        float4 bp4 = *(const float4*)(bp + o0);
        float4 xr = *(float4*)(xs + t * XSTR + o0);
        float4 o;
        {
            float g = g4.x + bg4.x, p = p4.x + bp4.x;
            o.x = fmaf(p * (1.f / (1.f + __expf(-g))), 1.f / (1.f + __expf(-p)), xr.x);
        }
        {
            float g = g4.y + bg4.y, p = p4.y + bp4.y;
            o.y = fmaf(p * (1.f / (1.f + __expf(-g))), 1.f / (1.f + __expf(-p)), xr.y);
        }
        {
            float g = g4.z + bg4.z, p = p4.z + bp4.z;
            o.z = fmaf(p * (1.f / (1.f + __expf(-g))), 1.f / (1.f + __expf(-p)), xr.z);
        }
        {
            float g = g4.w + bg4.w, p = p4.w + bp4.w;
            o.w = fmaf(p * (1.f / (1.f + __expf(-g))), 1.f / (1.f + __expf(-p)), xr.w);
        }
        *(float4*)(out + (size_t)(t0 + t) * 64 + o0) = o;
    }
}

extern "C" void kernel_launch(void* const* d_in, const int* in_sizes, int n_in,
                              void* d_out, int out_size, void* d_ws, size_t ws_size,
                              hipStream_t stream) {
    (void)in_sizes; (void)n_in; (void)out_size; (void)ws_size;
    const float* x    = (const float*)d_in[0];
    const float* fm   = (const float*)d_in[1];
    const float* phs  = (const float*)d_in[2];
    const float* fs   = (const float*)d_in[3];
    const float* Wq   = (const float*)d_in[4];
    const float* bq   = (const float*)d_in[5];
    const float* Wk1  = (const float*)d_in[6];
    // d_in[7] = bk1: affine shift, cancels in softmax
    const float* Wqi  = (const float*)d_in[8];
    const float* bqi  = (const float*)d_in[9];
    const float* Wki  = (const float*)d_in[10];
    // d_in[11] = bki: cancels in softmax
    const float* Wg   = (const float*)d_in[12];
    const float* bg   = (const float*)d_in[13];
    const float* Wp   = (const float*)d_in[14];
    const float* bp   = (const float*)d_in[15];
    float* out = (float*)d_out;
    float* ws  = (float*)d_ws;

    aff_pre<<<BFRAG_ELEMS / 256, 256, 0, stream>>>(Wq, bq, Wk1, Wqi, bqi, Wki, Wg, Wp, ws);

    const unsigned short* Bf = (const unsigned short*)ws;
    const float* WP = ws + 135168;
    const float* cP = WP + 256;
    aff_main<<<NBLK, 256, 0, stream>>>(x, fm, fs, phs, Bf, WP, cP, bg, bp, out);
}

// Round 3
// 120.144 us; speedup vs baseline: 3.1190x; 1.4508x over previous
//
#include <hip/hip_runtime.h>
#include <math.h>

#define SS 2048
#define DIN 2112
#define NKT 66            // K tiles of 32 (kt 0,1 = x; kt 2+i = fourier d=i)
#define TOK 16            // tokens per block
#define NBLK 1024
#define ASTR 264          // A chunk row stride (bf16): 132 dw == 4 mod 32 -> 2-way max
#define XSTR 68           // xs row stride (fp32)
#define XBSTR 72          // xb row stride (bf16): 36 dw == 4 mod 32
#define CSTR 132          // C buffer row stride (fp32)
#define BFRAG_ELEMS (NKT * 8 * 64 * 8)   // 270336 ushort
#define LOG2E 1.4426950408889634f
#define INV2PI 0.15915494309189535f

typedef __attribute__((ext_vector_type(4))) float f32x4;
typedef __attribute__((ext_vector_type(8))) short bf16x8;

__device__ __forceinline__ unsigned short f2bf(float x) {
    union { float f; unsigned u; } v; v.f = x;
    unsigned r = v.u + 0x7FFFu + ((v.u >> 16) & 1u);
    return (unsigned short)(r >> 16);
}

// pack two fp32 -> packed bf16 (RNE sans tie-to-even exactness: +0x7fff+lsb then take high halves)
__device__ __forceinline__ unsigned pk2bf(float a, float b) {
    union { float f; unsigned u; } ua, ub; ua.f = a; ub.f = b;
    unsigned ra = ua.u + 0x7FFFu + ((ua.u >> 16) & 1u);
    unsigned rb = ub.u + 0x7FFFu + ((ub.u >> 16) & 1u);
#if __has_builtin(__builtin_amdgcn_perm)
    return __builtin_amdgcn_perm(rb, ra, 0x07060302u);  // [a.b2,a.b3,b.b2,b.b3]
#else
    return (ra >> 16) | (rb & 0xFFFF0000u);
#endif
}

#if __has_builtin(__builtin_amdgcn_exp2f)
#define EXP2(x) __builtin_amdgcn_exp2f(x)
#else
#define EXP2(x) exp2f(x)
#endif
#if __has_builtin(__builtin_amdgcn_sinf)
#define SINR(x) __builtin_amdgcn_sinf(x)   // sin(2*pi*x), x in revolutions
#define COSR(x) __builtin_amdgcn_cosf(x)
#else
#define SINR(x) __sinf(6.283185307179586f * (x))
#define COSR(x) __cosf(6.283185307179586f * (x))
#endif

// ---------------- precompute: pack B fragment-major bf16, fold attention to WP/cP ----------------
// ws layout: [0, 540672 B) Bfrag ushort[66][8][64][8]
//            floats at +135168: WP[4][64] (log2e-folded), then cP[4]
__global__ __launch_bounds__(256) void aff_pre(
    const float* __restrict__ Wq, const float* __restrict__ bq,
    const float* __restrict__ Wk1,
    const float* __restrict__ Wqi, const float* __restrict__ bqi,
    const float* __restrict__ Wki,
    const float* __restrict__ Wg, const float* __restrict__ Wp,
    float* __restrict__ ws)
{
    unsigned short* Bf = (unsigned short*)ws;
    float* WP = ws + 135168;
    float* cP = WP + 256;
    const int tid = threadIdx.x;
    const int gid = blockIdx.x * 256 + tid;   // < 270336 exactly

    {
        int j  = gid & 7;
        int q  = (gid >> 3) & 3;
        int nl = (gid >> 5) & 15;
        int nt = (gid >> 9) & 7;
        int kt = gid >> 12;
        int k = kt * 32 + q * 8 + j;
        int n = nt * 16 + nl;
        float s = (n < 64) ? Wg[(size_t)n * DIN + k] : Wp[(size_t)(n - 64) * DIN + k];
        int dst = ((kt * 8 + nt) * 64 + q * 16 + nl) * 8 + j;
        Bf[dst] = f2bf(s);
    }

    if (blockIdx.x == 0) {
        __shared__ float u[32];
        if (tid < 32) {
            float s = 0.f;
            #pragma unroll
            for (int a = 0; a < 32; ++a) s += Wki[tid * 32 + a] * Wk1[a];
            u[tid] = s;
        }
        __syncthreads();
        {
            const int h = tid >> 6;     // 0..3
            const int d = tid & 63;     // 0..63
            float s = 0.f;
            for (int j = 0; j < 8; ++j) {
                int e = h * 8 + j;
                float wc = 0.f;
                #pragma unroll
                for (int a = 0; a < 32; ++a) wc += Wqi[e * 32 + a] * Wq[a * 64 + d];
                s += u[e] * wc;
            }
            WP[h * 64 + d] = s * 0.35355339059327373f * LOG2E;  // 1/sqrt(8), exp2-domain
            if (d == 0) {
                float sc = 0.f;
                for (int j = 0; j < 8; ++j) {
                    int e = h * 8 + j;
                    float bcv = bqi[e];
                    #pragma unroll
                    for (int a = 0; a < 32; ++a) bcv += Wqi[e * 32 + a] * bq[a];
                    sc += u[e] * bcv;
                }
                cP[h] = sc * 0.35355339059327373f * LOG2E;
            }
        }
    }
}

// ---------------- main fused kernel ----------------
// 16 tokens/block, 256 threads = 4 waves. Wave w: m-tile = all 16 tokens, n-tiles {2w, 2w+1}.
// Build lanes: token = lane&15, fh = (lane>>4)&1 (f-half), dsel = lane>>5; wave builds d = ch*8 + 2w + dsel.
__global__ __launch_bounds__(256, 4) void aff_main(
    const float* __restrict__ x,
    const float* __restrict__ fm, const float* __restrict__ fs,
    const float* __restrict__ phase,
    const unsigned short* __restrict__ Bf,
    const float* __restrict__ WP, const float* __restrict__ cP,
    const float* __restrict__ bg, const float* __restrict__ bp,
    float* __restrict__ out)
{
    __shared__ __align__(16) float xs[TOK * XSTR];               // 4352 B
    __shared__ __align__(16) unsigned short xb[TOK * XBSTR];     // 2304 B
    __shared__ __align__(16) unsigned short Ab[2][TOK * ASTR];   // 2 x 8448 B
    __shared__ __align__(16) float fv[1024];                     // 4096 B
    __shared__ __align__(16) float phr[1024];                    // 4096 B (phase / 2pi)
    __shared__ __align__(16) float Pl[TOK * 4];                  // 256 B (log2e-folded)
    __shared__ __align__(16) float flmx[128];                    // per-d {max_f, min_f} of fv

    const int tid  = threadIdx.x;
    const int lane = tid & 63;
    const int w    = tid >> 6;
    const int t0   = blockIdx.x * TOK;
    const int lm   = lane & 15;
    const int lq   = lane >> 4;
    const int fh   = lq & 1;
    const int dsel = lane >> 5;
    const int dloc = (w << 1) + dsel;        // 0..7 within chunk

    // ---- stage ----
    {
        float4 a = ((const float4*)fm)[tid];
        float4 b = ((const float4*)fs)[tid];
        float4 r; r.x = a.x * b.x; r.y = a.y * b.y; r.z = a.z * b.z; r.w = a.w * b.w;
        ((float4*)fv)[tid] = r;
        float4 p = ((const float4*)phase)[tid];
        p.x *= INV2PI; p.y *= INV2PI; p.z *= INV2PI; p.w *= INV2PI;
        ((float4*)phr)[tid] = p;
    }
    {
        int t = tid >> 4, j4 = (tid & 15) * 4;
        float4 xv = *(const float4*)(x + (size_t)(t0 + t) * 64 + j4);
        *(float4*)(xs + t * XSTR + j4) = xv;
        unsigned short* xbp = xb + t * XBSTR + j4;
        xbp[0] = f2bf(xv.x); xbp[1] = f2bf(xv.y); xbp[2] = f2bf(xv.z); xbp[3] = f2bf(xv.w);
    }
    __syncthreads();

    // ---- P (exp2-domain) and per-d minmax ----
    if (tid < 64) {
        int t = tid & 15, h = tid >> 4;
        float acc = cP[h];
        const float* wp = WP + h * 64;
        #pragma unroll 8
        for (int d = 0; d < 64; ++d) acc = fmaf(wp[d], xs[t * XSTR + d], acc);
        Pl[t * 4 + h] = acc;
    } else if (tid < 128) {
        int d = tid - 64;
        float mx = -1e30f, mn = 1e30f;
        #pragma unroll
        for (int f = 0; f < 16; ++f) {
            float v = fv[d * 16 + f];
            mx = fmaxf(mx, v); mn = fminf(mn, v);
        }
        flmx[d * 2] = mx; flmx[d * 2 + 1] = mn;
    }

    f32x4 acc0 = {}, acc1 = {};
    const bf16x8* Bv = (const bf16x8*)Bf;

    // ---- x part (kt 0,1) ----
    #pragma unroll
    for (int ks = 0; ks < 2; ++ks) {
        bf16x8 a = *(const bf16x8*)(xb + lm * XBSTR + ks * 32 + lq * 8);
        bf16x8 b0 = Bv[((size_t)ks * 8 + 2 * w) * 64 + lane];
        bf16x8 b1 = Bv[((size_t)ks * 8 + 2 * w + 1) * 64 + lane];
        acc0 = __builtin_amdgcn_mfma_f32_16x16x32_bf16(a, b0, acc0, 0, 0, 0);
        acc1 = __builtin_amdgcn_mfma_f32_16x16x32_bf16(a, b1, acc1, 0, 0, 0);
    }
    __syncthreads();   // Pl, flmx ready

    const float w2 = (float)((t0 + lm) & (SS - 1)) * (1.0f / 2047.0f);  // revolutions/unit-freq

    // builder: compute chunk ch's A rows for this lane into Ab[buf]
    auto build = [&](int ch, int buf) {
        const int d = ch * 8 + dloc;
        const float4 fA = *(const float4*)(fv + d * 16 + fh * 8);
        const float4 fB = *(const float4*)(fv + d * 16 + fh * 8 + 4);
        const float4 pA = *(const float4*)(phr + d * 16 + fh * 8);
        const float4 pB = *(const float4*)(phr + d * 16 + fh * 8 + 4);
        const float4 Pv = *(const float4*)(Pl + lm * 4);
        const float mxv = flmx[d * 2], mnv = flmx[d * 2 + 1];
        float fl[8] = {fA.x, fA.y, fA.z, fA.w, fB.x, fB.y, fB.z, fB.w};
        float pr[8] = {pA.x, pA.y, pA.z, pA.w, pB.x, pB.y, pB.z, pB.w};
        float aw[8] = {0.f, 0.f, 0.f, 0.f, 0.f, 0.f, 0.f, 0.f};
        float Ph4[4] = {Pv.x, Pv.y, Pv.z, Pv.w};
        #pragma unroll
        for (int h = 0; h < 4; ++h) {
            float Ph = Ph4[h];
            float m = fmaxf(mxv * Ph, mnv * Ph);   // exact max over all 16 f (monotone in fl)
            float e[8]; float s = 0.f;
            #pragma unroll
            for (int j = 0; j < 8; ++j) { e[j] = EXP2(fmaf(fl[j], Ph, -m)); s += e[j]; }
            float z = s + __shfl_xor(s, 16);       // other f-half (dup across sin/cos pair ok)
            float inv = 0.25f / z;                 // head-mean folded
            #pragma unroll
            for (int j = 0; j < 8; ++j) aw[j] = fmaf(e[j], inv, aw[j]);
        }
        unsigned sv[4], cv[4];
        #pragma unroll
        for (int jp = 0; jp < 4; ++jp) {
            int j0 = 2 * jp;
            float X0 = fmaf(w2, fl[j0], pr[j0]);
            float X1 = fmaf(w2, fl[j0 + 1], pr[j0 + 1]);
            float a0 = aw[j0], a1 = aw[j0 + 1];
            sv[jp] = pk2bf(a0 * SINR(X0), a1 * SINR(X1));
            cv[jp] = pk2bf(a0 * COSR(X0), a1 * COSR(X1));
        }
        unsigned short* dst = &Ab[buf][lm * ASTR + dloc * 32 + fh * 8];
        uint4 v0; v0.x = sv[0]; v0.y = sv[1]; v0.z = sv[2]; v0.w = sv[3];
        uint4 v1; v1.x = cv[0]; v1.y = cv[1]; v1.z = cv[2]; v1.w = cv[3];
        *(uint4*)dst = v0;
        *(uint4*)(dst + 16) = v1;
    };

    build(0, 0);
    __syncthreads();

    // ---- pipelined K loop: MFMA chunk ch from Ab[ch&1], build ch+1 into Ab[(ch+1)&1] ----
    for (int ch = 0; ch < 8; ++ch) {
        const unsigned short* Ar = &Ab[ch & 1][0];
        #pragma unroll
        for (int ks = 0; ks < 8; ++ks) {
            const size_t kt = (size_t)(2 + ch * 8 + ks);
            bf16x8 a = *(const bf16x8*)(Ar + lm * ASTR + ks * 32 + lq * 8);
            bf16x8 b0 = Bv[(kt * 8 + 2 * w) * 64 + lane];
            bf16x8 b1 = Bv[(kt * 8 + 2 * w + 1) * 64 + lane];
            acc0 = __builtin_amdgcn_mfma_f32_16x16x32_bf16(a, b0, acc0, 0, 0, 0);
            acc1 = __builtin_amdgcn_mfma_f32_16x16x32_bf16(a, b1, acc1, 0, 0, 0);
        }
        if (ch < 7) build(ch + 1, (ch + 1) & 1);
        __syncthreads();
    }

    // ---- epilogue ----
    float* Cb = (float*)(&Ab[0][0]);   // 16*132*4 = 8448 B, fits Ab[0]
    #pragma unroll
    for (int r = 0; r < 4; ++r) {
        Cb[(lq * 4 + r) * CSTR + (2 * w) * 16 + lm]     = acc0[r];
        Cb[(lq * 4 + r) * CSTR + (2 * w + 1) * 16 + lm] = acc1[r];
    }
    __syncthreads();
    {
        int t = tid >> 4, o0 = (tid & 15) * 4;
        float4 g4 = *(float4*)(Cb + t * CSTR + o0);
        float4 p4 = *(float4*)(Cb + t * CSTR + 64 + o0);
        float4 bg4 = *(const float4*)(bg + o0);
        float4 bp4 = *(const float4*)(bp + o0);
        float4 xr = *(float4*)(xs + t * XSTR + o0);
        float4 o;
        { float g = g4.x + bg4.x, p = p4.x + bp4.x;
          o.x = fmaf(p * (1.f / (1.f + __expf(-g))), 1.f / (1.f + __expf(-p)), xr.x); }
        { float g = g4.y + bg4.y, p = p4.y + bp4.y;
          o.y = fmaf(p * (1.f / (1.f + __expf(-g))), 1.f / (1.f + __expf(-p)), xr.y); }
        { float g = g4.z + bg4.z, p = p4.z + bp4.z;
          o.z = fmaf(p * (1.f / (1.f + __expf(-g))), 1.f / (1.f + __expf(-p)), xr.z); }
        { float g = g4.w + bg4.w, p = p4.w + bp4.w;
          o.w = fmaf(p * (1.f / (1.f + __expf(-g))), 1.f / (1.f + __expf(-p)), xr.w); }
        *(float4*)(out + (size_t)(t0 + t) * 64 + o0) = o;
    }
}

extern "C" void kernel_launch(void* const* d_in, const int* in_sizes, int n_in,
                              void* d_out, int out_size, void* d_ws, size_t ws_size,
                              hipStream_t stream) {
    (void)in_sizes; (void)n_in; (void)out_size; (void)ws_size;
    const float* x    = (const float*)d_in[0];
    const float* fm   = (const float*)d_in[1];
    const float* phs  = (const float*)d_in[2];
    const float* fs   = (const float*)d_in[3];
    const float* Wq   = (const float*)d_in[4];
    const float* bq   = (const float*)d_in[5];
    const float* Wk1  = (const float*)d_in[6];
    // d_in[7] = bk1: cancels in softmax
    const float* Wqi  = (const float*)d_in[8];
    const float* bqi  = (const float*)d_in[9];
    const float* Wki  = (const float*)d_in[10];
    // d_in[11] = bki: cancels in softmax
    const float* Wg   = (const float*)d_in[12];
    const float* bg   = (const float*)d_in[13];
    const float* Wp   = (const float*)d_in[14];
    const float* bp   = (const float*)d_in[15];
    float* out = (float*)d_out;
    float* ws  = (float*)d_ws;

    aff_pre<<<BFRAG_ELEMS / 256, 256, 0, stream>>>(Wq, bq, Wk1, Wqi, bqi, Wki, Wg, Wp, ws);

    const unsigned short* Bf = (const unsigned short*)ws;
    const float* WP = ws + 135168;
    const float* cP = WP + 256;
    aff_main<<<NBLK, 256, 0, stream>>>(x, fm, fs, phs, Bf, WP, cP, bg, bp, out);
}